// Round 10
// baseline (276.541 us; speedup 1.0000x reference)
//
#include <hip/hip_runtime.h>
#include <hip/hip_bf16.h>
#include <stdint.h>

#define N_NODES 100000
#define IN_F    512
#define OUT_F   256
#define N_EDGES 1600000

typedef __attribute__((ext_vector_type(4))) float f32x4;
typedef __attribute__((ext_vector_type(8))) short bf16x8;
typedef __attribute__((ext_vector_type(8))) uint16_t u16x8;
typedef __attribute__((ext_vector_type(4))) uint32_t u32x4;

#define BM 128
#define BK 32
#define KT_TILES (IN_F / BK)             // 16
#define WFRAG_KT_STRIDE (16 * 16 * 32)   // 8192 elems per kt slab
#define EPS 66                            // epilogue LDS row stride (bf16)

#define NBUCK 196                         // ceil(100000/512) buckets of 512 nodes
#define SC_EDGES 8192                     // edges per bucket_scatter block
#define NBLK_SC ((N_EDGES + SC_EDGES - 1) / SC_EDGES)   // 196

#define SCAN_CHUNK 4096
#define NCHUNKS ((N_NODES + SCAN_CHUNK - 1) / SCAN_CHUNK)   // 25

__device__ __forceinline__ float bf2f(uint16_t u) {
    union { uint32_t i; float f; } c; c.i = ((uint32_t)u) << 16; return c.f;
}
__device__ __forceinline__ uint16_t f2bf(float f) {
    union { float f; uint32_t i; } c; c.f = f;
    uint32_t x = c.i;
    return (uint16_t)((x + 0x7FFFu + ((x >> 16) & 1u)) >> 16);  // RNE
}
__device__ __forceinline__ uint32_t cvt_pk_bf16(float a, float b) {
    uint32_t r;
    asm("v_cvt_pk_bf16_f32 %0, %1, %2" : "=v"(r) : "v"(a), "v"(b));
    return r;
}
// async global->LDS, 16B per lane; LDS dest = wave-uniform base + lane*16
__device__ __forceinline__ void gload_lds16(const float* g, float* l) {
    __builtin_amdgcn_global_load_lds(
        (const __attribute__((address_space(1))) void*)g,
        (__attribute__((address_space(3))) void*)l, 16, 0, 0);
}

// ---------------- W -> bf16 fragment-order ----------------
__global__ __launch_bounds__(256) void w_frag_kernel(
    const float* __restrict__ W, uint16_t* __restrict__ w_frag)
{
    const int gid = blockIdx.x * 256 + threadIdx.x;   // 16384 groups of 8 elems
    if (gid >= 16384) return;
    const int kg = gid & 3, lrow = (gid >> 2) & 15, cg = (gid >> 6) & 15, kt = gid >> 10;
    const float* s = W + (size_t)(cg * 16 + lrow) * IN_F + kt * 32 + kg * 8;
    const f32x4 v0 = *(const f32x4*)s;
    const f32x4 v1 = *(const f32x4*)(s + 4);
    u32x4 c;
    c[0] = cvt_pk_bf16(v0[0], v0[1]);
    c[1] = cvt_pk_bf16(v0[2], v0[3]);
    c[2] = cvt_pk_bf16(v1[0], v1[1]);
    c[3] = cvt_pk_bf16(v1[2], v1[3]);
    *(u32x4*)(w_frag + (size_t)gid * 8) = c;
}

// ---------------- GEMM: h = bf16(feat @ W^T + b) (proven R7 version) ----------
__global__ __launch_bounds__(512) void gcn_gemm_kernel(
    const float* __restrict__ feat, const uint16_t* __restrict__ w_frag,
    const float* __restrict__ bias, uint16_t* __restrict__ h)
{
    __shared__ __align__(16) char smem_raw[2 * BM * BK * 4];   // 32 KB
    float (*At)[BM][BK] = (float (*)[BM][BK])smem_raw;

    const int m0 = blockIdx.x * BM;

    const int t    = threadIdx.x;
    const int wid  = t >> 6;
    const int lane = t & 63;
    const int wr   = wid >> 2, wc = wid & 3;   // 2x4 waves, 64x64 tile per wave
    const int lrow = lane & 15;
    const int kg   = lane >> 4;

    f32x4 acc[4][4] = {};

    const int r8 = lane >> 3;
    const int sp = lane & 7;
    const int sc = sp ^ r8;            // source-side swizzle
    const float* gsrc[2];
    #pragma unroll
    for (int i = 0; i < 2; ++i) {
        int grow = m0 + wid * 16 + i * 8 + r8;
        if (grow > N_NODES - 1) grow = N_NODES - 1;
        gsrc[i] = feat + (size_t)grow * IN_F + sc * 4;
    }

#define STAGE(KT, BUF)                                                     \
    do {                                                                   \
        gload_lds16(gsrc[0] + (KT) * BK, &At[BUF][wid * 16][0]);           \
        gload_lds16(gsrc[1] + (KT) * BK, &At[BUF][wid * 16 + 8][0]);       \
    } while (0)

    const uint16_t* wfp[4];
    #pragma unroll
    for (int n = 0; n < 4; ++n) {
        const int cg = wc * 4 + n;
        wfp[n] = w_frag + ((size_t)cg * 16 + lrow) * 32 + kg * 8;
    }

    bf16x8 bfr[2][4];

    STAGE(0, 0);
    #pragma unroll
    for (int n = 0; n < 4; ++n) bfr[0][n] = *(const bf16x8*)(wfp[n]);
    __syncthreads();

    const int p0 = (2 * kg) ^ (lrow & 7);   // read-side swizzle
    const int p1 = p0 ^ 1;

    #pragma unroll
    for (int kt = 0; kt < KT_TILES; ++kt) {
        const int cur = kt & 1, nxt = cur ^ 1;
        if (kt + 1 < KT_TILES) {
            STAGE(kt + 1, nxt);
            #pragma unroll
            for (int n = 0; n < 4; ++n)
                bfr[nxt][n] = *(const bf16x8*)(wfp[n] + (size_t)(kt + 1) * WFRAG_KT_STRIDE);
        }
        bf16x8 af[4];
        #pragma unroll
        for (int m = 0; m < 4; ++m) {
            const int row = wr * 64 + m * 16 + lrow;
            const f32x4 v0 = *(const f32x4*)&At[cur][row][p0 * 4];
            const f32x4 v1 = *(const f32x4*)&At[cur][row][p1 * 4];
            union { bf16x8 v; uint32_t u[4]; } c_;
            c_.u[0] = cvt_pk_bf16(v0[0], v0[1]);
            c_.u[1] = cvt_pk_bf16(v0[2], v0[3]);
            c_.u[2] = cvt_pk_bf16(v1[0], v1[1]);
            c_.u[3] = cvt_pk_bf16(v1[2], v1[3]);
            af[m] = c_.v;
        }
        #pragma unroll
        for (int m = 0; m < 4; ++m)
            #pragma unroll
            for (int n = 0; n < 4; ++n)
                acc[m][n] = __builtin_amdgcn_mfma_f32_16x16x32_bf16(
                    af[m], bfr[cur][n], acc[m][n], 0, 0, 0);
        if (kt + 1 < KT_TILES) __syncthreads();
    }
#undef STAGE

    __syncthreads();

    uint16_t* ep = (uint16_t*)smem_raw;
    const int wbase = wid * (16 * EPS);
    float bv[4];
    #pragma unroll
    for (int n = 0; n < 4; ++n) bv[n] = bias[wc * 64 + n * 16 + lrow];

    #pragma unroll
    for (int m = 0; m < 4; ++m) {
        #pragma unroll
        for (int n = 0; n < 4; ++n)
            #pragma unroll
            for (int j = 0; j < 4; ++j)
                ep[wbase + (kg * 4 + j) * EPS + n * 16 + lrow] = f2bf(acc[m][n][j] + bv[n]);
        __syncthreads();
        #pragma unroll
        for (int g = 0; g < 4; ++g) {
            const int r16  = g * 4 + (lane >> 4);
            const int cidx = (lane & 15) * 4;
            const int ib = wbase + r16 * EPS + cidx;
            uint2 v;
            v.x = *(const uint32_t*)&ep[ib];
            v.y = *(const uint32_t*)&ep[ib + 2];
            const int row = m0 + wr * 64 + m * 16 + r16;
            if (row < N_NODES)
                *(uint2*)(h + (size_t)row * OUT_F + wc * 64 + cidx) = v;
        }
        __syncthreads();
    }
}

// ================= bucketed CSR build =================
// pass 1: per-block bucket histograms (no global atomics, no memset needed)
__global__ __launch_bounds__(256) void bucket_count_kernel(
    const int* __restrict__ dst, int* __restrict__ blockHist)
{
    __shared__ int bh[NBUCK];
    for (int i = threadIdx.x; i < NBUCK; i += 256) bh[i] = 0;
    __syncthreads();
    const int base = blockIdx.x * SC_EDGES;
    #pragma unroll
    for (int k = 0; k < SC_EDGES / 256; ++k) {
        const int e = base + k * 256 + threadIdx.x;
        if (e < N_EDGES) atomicAdd(&bh[dst[e] >> 9], 1);
    }
    __syncthreads();
    for (int i = threadIdx.x; i < NBUCK; i += 256)
        blockHist[blockIdx.x * NBUCK + i] = bh[i];
}

// pass 2: column-sum blockHist -> totals; exclusive scan -> base + cursor
__global__ void bucket_scan_kernel(const int* __restrict__ blockHist,
                                   int* __restrict__ bucket_base,
                                   int* __restrict__ bucket_cursor)
{
    __shared__ int sc[256];
    const int t = threadIdx.x;
    int v = 0;
    if (t < NBUCK) {
        #pragma unroll 4
        for (int b = 0; b < NBLK_SC; ++b) v += blockHist[b * NBUCK + t];
    }
    int x = v;
    sc[t] = x; __syncthreads();
    for (int off = 1; off < 256; off <<= 1) {
        const int y = (t >= off) ? sc[t - off] : 0;
        __syncthreads();
        x += y; sc[t] = x;
        __syncthreads();
    }
    if (t < NBUCK) {
        const int ex = x - v;
        bucket_base[t] = ex;
        bucket_cursor[t] = ex;
    }
    if (t == 0) bucket_base[NBUCK] = N_EDGES;
}

// pass 3: scatter packed (src<<9 | dst&511) into bucket-major order.
__global__ __launch_bounds__(256) void bucket_scatter_kernel(
    const int* __restrict__ src, const int* __restrict__ dst,
    int* __restrict__ bucket_cursor, uint32_t* __restrict__ pairs)
{
    __shared__ int bh[NBUCK];
    __shared__ int bbase[NBUCK];
    for (int i = threadIdx.x; i < NBUCK; i += 256) bh[i] = 0;
    __syncthreads();
    const int base = blockIdx.x * SC_EDGES;
    uint32_t pk[SC_EDGES / 256];
    int      bk[SC_EDGES / 256];
    #pragma unroll
    for (int k = 0; k < SC_EDGES / 256; ++k) {
        const int e = base + k * 256 + threadIdx.x;
        if (e < N_EDGES) {
            const int d = dst[e], s = src[e];
            bk[k] = d >> 9;
            pk[k] = ((uint32_t)s << 9) | (uint32_t)(d & 511);
            atomicAdd(&bh[bk[k]], 1);
        } else {
            bk[k] = -1; pk[k] = 0;
        }
    }
    __syncthreads();
    for (int i = threadIdx.x; i < NBUCK; i += 256) {
        const int c = bh[i];
        bbase[i] = c ? atomicAdd(&bucket_cursor[i], c) : 0;
        bh[i] = 0;
    }
    __syncthreads();
    #pragma unroll
    for (int k = 0; k < SC_EDGES / 256; ++k) {
        if (bk[k] >= 0) {
            const int r = atomicAdd(&bh[bk[k]], 1);
            pairs[bbase[bk[k]] + r] = pk[k];
        }
    }
}

// pass 4: per-bucket counting sort -> start[] + csr_src (block-local region)
__global__ __launch_bounds__(256) void bucket_sort_kernel(
    const uint32_t* __restrict__ pairs, const int* __restrict__ bucket_base,
    int* __restrict__ start, int* __restrict__ csr_src)
{
    __shared__ int hist[512];
    __shared__ int tsum[256];
    const int b = blockIdx.x;
    const int t = threadIdx.x;
    const int ebeg = bucket_base[b], eend = bucket_base[b + 1];
    hist[t] = 0; hist[t + 256] = 0;
    __syncthreads();
    for (int i = ebeg + t; i < eend; i += 256)
        atomicAdd(&hist[pairs[i] & 511], 1);
    __syncthreads();
    const int c0 = hist[2 * t], c1 = hist[2 * t + 1];
    int x = c0 + c1;
    tsum[t] = x; __syncthreads();
    for (int off = 1; off < 256; off <<= 1) {
        const int y = (t >= off) ? tsum[t - off] : 0;
        __syncthreads();
        x += y; tsum[t] = x;
        __syncthreads();
    }
    const int ex = x - (c0 + c1);     // exclusive prefix over thread pairs
    __syncthreads();                  // all c0/c1 reads done before overwrite
    hist[2 * t] = ex;
    hist[2 * t + 1] = ex + c0;
    const int nb0 = b << 9;
    if (nb0 + 2 * t < N_NODES)     start[nb0 + 2 * t]     = ebeg + ex;
    if (nb0 + 2 * t + 1 < N_NODES) start[nb0 + 2 * t + 1] = ebeg + ex + c0;
    __syncthreads();
    for (int i = ebeg + t; i < eend; i += 256) {
        const uint32_t p = pairs[i];
        const int pos = ebeg + atomicAdd(&hist[p & 511], 1);
        csr_src[pos] = (int)(p >> 9);
    }
}

// ---------------- legacy CSR build (fallback if ws too small) ----------------
__global__ __launch_bounds__(256) void hist_kernel(
    const int* __restrict__ dst, int* __restrict__ deg)
{
    const int e = blockIdx.x * 256 + threadIdx.x;
    if (e < N_EDGES) atomicAdd(&deg[dst[e]], 1);
}

__global__ __launch_bounds__(256) void chunk_reduce_kernel(
    const int* __restrict__ deg, int* __restrict__ chunkSum)
{
    __shared__ int red[256];
    const int b = blockIdx.x, t = threadIdx.x;
    const int base = b * SCAN_CHUNK;
    int s = 0;
    #pragma unroll
    for (int i = 0; i < 16; ++i) {
        const int idx = base + t * 16 + i;
        s += (idx < N_NODES) ? deg[idx] : 0;
    }
    red[t] = s;
    __syncthreads();
    for (int off = 128; off > 0; off >>= 1) {
        if (t < off) red[t] += red[t + off];
        __syncthreads();
    }
    if (t == 0) chunkSum[b] = red[0];
}

__global__ void scan_chunksums_kernel(const int* __restrict__ chunkSum,
                                      int* __restrict__ chunkOff)
{
    if (threadIdx.x == 0 && blockIdx.x == 0) {
        int acc = 0;
        for (int i = 0; i < NCHUNKS; ++i) { chunkOff[i] = acc; acc += chunkSum[i]; }
    }
}

__global__ __launch_bounds__(256) void chunk_scan_kernel(
    const int* __restrict__ deg, const int* __restrict__ chunkOff,
    int* __restrict__ start, int* __restrict__ cursor)
{
    __shared__ int tsum[256];
    const int b = blockIdx.x, t = threadIdx.x;
    const int base = b * SCAN_CHUNK;
    int vals[16];
    int s = 0;
    #pragma unroll
    for (int i = 0; i < 16; ++i) {
        const int idx = base + t * 16 + i;
        const int v = (idx < N_NODES) ? deg[idx] : 0;
        vals[i] = s;
        s += v;
    }
    int x = s;
    tsum[t] = x;
    __syncthreads();
    #pragma unroll
    for (int off = 1; off < 256; off <<= 1) {
        const int y = (t >= off) ? tsum[t - off] : 0;
        __syncthreads();
        x += y;
        tsum[t] = x;
        __syncthreads();
    }
    const int thread_off = chunkOff[b] + (t == 0 ? 0 : tsum[t - 1]);
    #pragma unroll
    for (int i = 0; i < 16; ++i) {
        const int idx = base + t * 16 + i;
        if (idx < N_NODES) {
            const int st = thread_off + vals[i];
            start[idx] = st;
            cursor[idx] = st;
        }
    }
}

__global__ __launch_bounds__(256) void csr_fill_kernel(
    const int* __restrict__ src, const int* __restrict__ dst,
    int* __restrict__ cursor, int* __restrict__ csr_src)
{
    const int e = blockIdx.x * 256 + threadIdx.x;
    if (e < N_EDGES) {
        const int d = dst[e];
        const int p = atomicAdd(&cursor[d], 1);
        csr_src[p] = src[e];
    }
}

// ---------------- gather v3: column-split pass + quarter-wave rows ----------
// Each pass handles 128 cols (256 B/row) -> 25.6 MB working set (L2-friendly).
// Wave = 4 quarter-groups of 16 lanes; quarter q processes edges j=beg+q,+4,..
// at 16 B/lane; unroll 2 -> 8 independent row loads in flight per wave.
// Combine quarters via shfl_xor(16), shfl_xor(32); lanes 0-15 store half-row.
__global__ __launch_bounds__(256) void gcn_gather_kernel(
    const uint16_t* __restrict__ h, const int* __restrict__ start,
    const int* __restrict__ csr_src, float* __restrict__ out, int pass)
{
    const int n = blockIdx.x * 4 + (threadIdx.x >> 6);
    if (n >= N_NODES) return;
    const int lane = threadIdx.x & 63;
    const int q  = lane >> 4;     // quarter 0..3
    const int hl = lane & 15;     // 16B chunk within the 256B half-row
    const int beg = start[n];
    const int end = (n == N_NODES - 1) ? N_EDGES : start[n + 1];
    const uint16_t* hb = h + pass * 128 + hl * 8;

    float a[8] = {0.f, 0.f, 0.f, 0.f, 0.f, 0.f, 0.f, 0.f};

    int j = beg + q;
    for (; j + 4 < end; j += 8) {
        const int s0 = csr_src[j];
        const int s1 = csr_src[j + 4];
        const u16x8 v0 = *(const u16x8*)(hb + (size_t)s0 * OUT_F);
        const u16x8 v1 = *(const u16x8*)(hb + (size_t)s1 * OUT_F);
        #pragma unroll
        for (int i = 0; i < 8; ++i) a[i] += bf2f(v0[i]);
        #pragma unroll
        for (int i = 0; i < 8; ++i) a[i] += bf2f(v1[i]);
    }
    if (j < end) {
        const int s0 = csr_src[j];
        const u16x8 v0 = *(const u16x8*)(hb + (size_t)s0 * OUT_F);
        #pragma unroll
        for (int i = 0; i < 8; ++i) a[i] += bf2f(v0[i]);
    }

    // combine the 4 quarters (all lanes end with the full sum)
    #pragma unroll
    for (int i = 0; i < 8; ++i) {
        a[i] += __shfl_xor(a[i], 16, 64);
        a[i] += __shfl_xor(a[i], 32, 64);
    }

    if (q == 0) {
        f32x4 o0, o1;
        o0[0] = a[0]; o0[1] = a[1]; o0[2] = a[2]; o0[3] = a[3];
        o1[0] = a[4]; o1[1] = a[5]; o1[2] = a[6]; o1[3] = a[7];
        float* op = out + (size_t)n * OUT_F + pass * 128 + hl * 8;
        *(f32x4*)op = o0;
        *(f32x4*)(op + 4) = o1;
    }
}

// ---------------- fallback atomic scatter (tiny ws) ----------------
__global__ __launch_bounds__(256) void gcn_scatter_kernel(
    const uint16_t* __restrict__ h, const int* __restrict__ src,
    const int* __restrict__ dst, float* __restrict__ out)
{
    const int e = (blockIdx.x << 2) | (threadIdx.x >> 6);
    if (e >= N_EDGES) return;
    const int lane = threadIdx.x & 63;
    const int s = src[e];
    const int d = dst[e];
    const ushort4 v = *((const ushort4*)(h + (size_t)s * OUT_F) + lane);
    float* op = out + (size_t)d * OUT_F + (lane << 2);
    unsafeAtomicAdd(op + 0, bf2f(v.x));
    unsafeAtomicAdd(op + 1, bf2f(v.y));
    unsafeAtomicAdd(op + 2, bf2f(v.z));
    unsafeAtomicAdd(op + 3, bf2f(v.w));
}

static inline size_t align256(size_t x) { return (x + 255) & ~(size_t)255; }

extern "C" void kernel_launch(void* const* d_in, const int* in_sizes, int n_in,
                              void* d_out, int out_size, void* d_ws, size_t ws_size,
                              hipStream_t stream) {
    const float* feat = (const float*)d_in[0];
    const float* W    = (const float*)d_in[1];
    const float* bias = (const float*)d_in[2];
    const int*   src  = (const int*)d_in[3];
    const int*   dst  = (const int*)d_in[4];
    float*       out  = (float*)d_out;

    char* ws = (char*)d_ws;

    // ---- bucketed layout ----
    size_t off = 0;
    uint16_t* h       = (uint16_t*)(ws + off); off = align256(off + (size_t)N_NODES * OUT_F * 2);
    uint16_t* w_frag  = (uint16_t*)(ws + off); off = align256(off + (size_t)OUT_F * IN_F * 2);
    int* start        = (int*)(ws + off);      off = align256(off + (size_t)N_NODES * 4);
    int* bucket_base  = (int*)(ws + off);      off = align256(off + (size_t)(NBUCK + 1) * 4);
    int* bucket_cursor= (int*)(ws + off);      off = align256(off + (size_t)NBUCK * 4);
    int* blockHist    = (int*)(ws + off);      off = align256(off + (size_t)NBLK_SC * NBUCK * 4);
    uint32_t* pairs   = (uint32_t*)(ws + off); off = align256(off + (size_t)N_EDGES * 4);
    int* csr_src      = (int*)(ws + off);      off = align256(off + (size_t)N_EDGES * 4);
    const bool bucket_ok = (off <= ws_size);

    const int mtiles = (N_NODES + BM - 1) / BM;  // 782

    w_frag_kernel<<<64, 256, 0, stream>>>(W, w_frag);
    gcn_gemm_kernel<<<mtiles, 512, 0, stream>>>(feat, w_frag, bias, h);

    if (bucket_ok) {
        bucket_count_kernel<<<NBLK_SC, 256, 0, stream>>>(dst, blockHist);
        bucket_scan_kernel<<<1, 256, 0, stream>>>(blockHist, bucket_base, bucket_cursor);
        bucket_scatter_kernel<<<NBLK_SC, 256, 0, stream>>>(src, dst, bucket_cursor, pairs);
        bucket_sort_kernel<<<NBUCK, 256, 0, stream>>>(pairs, bucket_base, start, csr_src);
        gcn_gather_kernel<<<(N_NODES + 3) / 4, 256, 0, stream>>>(h, start, csr_src, out, 0);
        gcn_gather_kernel<<<(N_NODES + 3) / 4, 256, 0, stream>>>(h, start, csr_src, out, 1);
        return;
    }

    // ---- legacy layout / path ----
    off = 0;
    h            = (uint16_t*)(ws + off); off = align256(off + (size_t)N_NODES * OUT_F * 2);
    w_frag       = (uint16_t*)(ws + off); off = align256(off + (size_t)OUT_F * IN_F * 2);
    int* deg     = (int*)(ws + off);      off = align256(off + (size_t)N_NODES * 4);
    start        = (int*)(ws + off);      off = align256(off + (size_t)N_NODES * 4);
    int* cursor  = (int*)(ws + off);      off = align256(off + (size_t)N_NODES * 4);
    int* chunkSum= (int*)(ws + off);      off = align256(off + (size_t)NCHUNKS * 4);
    int* chunkOff= (int*)(ws + off);      off = align256(off + (size_t)NCHUNKS * 4);
    csr_src      = (int*)(ws + off);      off = align256(off + (size_t)N_EDGES * 4);
    const bool csr_ok = (off <= ws_size);

    if (csr_ok) {
        hipMemsetAsync(deg, 0, (size_t)N_NODES * 4, stream);
        const int eblocks = (N_EDGES + 255) / 256;
        hist_kernel<<<eblocks, 256, 0, stream>>>(dst, deg);
        chunk_reduce_kernel<<<NCHUNKS, 256, 0, stream>>>(deg, chunkSum);
        scan_chunksums_kernel<<<1, 64, 0, stream>>>(chunkSum, chunkOff);
        chunk_scan_kernel<<<NCHUNKS, 256, 0, stream>>>(deg, chunkOff, start, cursor);
        csr_fill_kernel<<<eblocks, 256, 0, stream>>>(src, dst, cursor, csr_src);
        gcn_gather_kernel<<<(N_NODES + 3) / 4, 256, 0, stream>>>(h, start, csr_src, out, 0);
        gcn_gather_kernel<<<(N_NODES + 3) / 4, 256, 0, stream>>>(h, start, csr_src, out, 1);
    } else {
        hipMemsetAsync(out, 0, (size_t)out_size * sizeof(float), stream);
        gcn_scatter_kernel<<<(N_EDGES + 3) / 4, 256, 0, stream>>>(h, src, dst, out);
    }
}

// Round 11
// 245.914 us; speedup vs baseline: 1.1245x; 1.1245x over previous
//
#include <hip/hip_runtime.h>
#include <hip/hip_bf16.h>
#include <stdint.h>

#define N_NODES 100000
#define IN_F    512
#define OUT_F   256
#define N_EDGES 1600000

typedef __attribute__((ext_vector_type(4))) float f32x4;
typedef __attribute__((ext_vector_type(8))) short bf16x8;
typedef __attribute__((ext_vector_type(8))) uint16_t u16x8;
typedef __attribute__((ext_vector_type(4))) uint32_t u32x4;

#define BM 128
#define BK 32
#define KT_TILES (IN_F / BK)             // 16
#define WFRAG_KT_STRIDE (16 * 16 * 32)   // 8192 elems per kt slab
#define EPS 66                            // epilogue LDS row stride (bf16)

#define NBUCK 196                         // ceil(100000/512) buckets of 512 nodes
#define BCAP  9216                        // fixed bucket capacity (mean 8192, +11 sigma)
#define SC_EDGES 8192                     // edges per bucket_scatter block
#define NBLK_SC ((N_EDGES + SC_EDGES - 1) / SC_EDGES)   // 196

__device__ __forceinline__ float bf2f(uint16_t u) {
    union { uint32_t i; float f; } c; c.i = ((uint32_t)u) << 16; return c.f;
}
__device__ __forceinline__ uint16_t f2bf(float f) {
    union { float f; uint32_t i; } c; c.f = f;
    uint32_t x = c.i;
    return (uint16_t)((x + 0x7FFFu + ((x >> 16) & 1u)) >> 16);  // RNE
}
__device__ __forceinline__ uint32_t cvt_pk_bf16(float a, float b) {
    uint32_t r;
    asm("v_cvt_pk_bf16_f32 %0, %1, %2" : "=v"(r) : "v"(a), "v"(b));
    return r;
}
// async global->LDS, 16B per lane; LDS dest = wave-uniform base + lane*16
__device__ __forceinline__ void gload_lds16(const float* g, float* l) {
    __builtin_amdgcn_global_load_lds(
        (const __attribute__((address_space(1))) void*)g,
        (__attribute__((address_space(3))) void*)l, 16, 0, 0);
}
// counted-vmcnt barrier: waits until only N vmem ops remain, then raw barrier.
// The "memory" clobber fences memory-op motion across iterations, making the
// per-wave vmcnt ledger robust to within-iteration reordering.
#define SYNC_VM(N) do {                                        \
    asm volatile("s_waitcnt vmcnt(" #N ")" ::: "memory");      \
    __builtin_amdgcn_s_barrier();                              \
} while (0)

// ---------------- W -> bf16 fragment-order ----------------
__global__ __launch_bounds__(256) void w_frag_kernel(
    const float* __restrict__ W, uint16_t* __restrict__ w_frag)
{
    const int gid = blockIdx.x * 256 + threadIdx.x;   // 16384 groups of 8 elems
    if (gid >= 16384) return;
    const int kg = gid & 3, lrow = (gid >> 2) & 15, cg = (gid >> 6) & 15, kt = gid >> 10;
    const float* s = W + (size_t)(cg * 16 + lrow) * IN_F + kt * 32 + kg * 8;
    const f32x4 v0 = *(const f32x4*)s;
    const f32x4 v1 = *(const f32x4*)(s + 4);
    u32x4 c;
    c[0] = cvt_pk_bf16(v0[0], v0[1]);
    c[1] = cvt_pk_bf16(v0[2], v0[3]);
    c[2] = cvt_pk_bf16(v1[0], v1[1]);
    c[3] = cvt_pk_bf16(v1[2], v1[3]);
    *(u32x4*)(w_frag + (size_t)gid * 8) = c;
}

// ---------------- GEMM: h = bf16(feat @ W^T + b) ----------------
// 512 thr / 8 waves (2x4), BM=128 x BN=256. A: fp32 via global_load_lds into
// 3 LDS buffers, staged 2 tiles ahead; counted vmcnt(6) barriers keep the
// pipeline deep (never drain to 0 in the main loop). B: bf16 fragments from
// L2-resident w_frag, register double-buffered. Epilogue transposes per-wave
// 64x64 tiles through LDS for coalesced 8B h stores.
__global__ __launch_bounds__(512) void gcn_gemm_kernel(
    const float* __restrict__ feat, const uint16_t* __restrict__ w_frag,
    const float* __restrict__ bias, uint16_t* __restrict__ h)
{
    __shared__ __align__(16) char smem_raw[3 * BM * BK * 4];   // 48 KB
    float (*At)[BM][BK] = (float (*)[BM][BK])smem_raw;

    const int m0 = blockIdx.x * BM;

    const int t    = threadIdx.x;
    const int wid  = t >> 6;
    const int lane = t & 63;
    const int wr   = wid >> 2, wc = wid & 3;   // 2x4 waves, 64x64 tile per wave
    const int lrow = lane & 15;
    const int kg   = lane >> 4;

    f32x4 acc[4][4] = {};

    const int r8 = lane >> 3;
    const int sp = lane & 7;
    const int sc = sp ^ r8;            // source-side swizzle
    const float* gsrc[2];
    #pragma unroll
    for (int i = 0; i < 2; ++i) {
        int grow = m0 + wid * 16 + i * 8 + r8;
        if (grow > N_NODES - 1) grow = N_NODES - 1;
        gsrc[i] = feat + (size_t)grow * IN_F + sc * 4;
    }

#define STAGE(KT, BUF)                                                     \
    do {                                                                   \
        gload_lds16(gsrc[0] + (KT) * BK, &At[BUF][wid * 16][0]);           \
        gload_lds16(gsrc[1] + (KT) * BK, &At[BUF][wid * 16 + 8][0]);       \
    } while (0)

    const uint16_t* wfp[4];
    #pragma unroll
    for (int n = 0; n < 4; ++n) {
        const int cg = wc * 4 + n;
        wfp[n] = w_frag + ((size_t)cg * 16 + lrow) * 32 + kg * 8;
    }

    bf16x8 bfr[2][4];

    // ---- prologue: B(0), stage tiles 0 and 1; single full drain ----
    #pragma unroll
    for (int n = 0; n < 4; ++n) bfr[0][n] = *(const bf16x8*)(wfp[n]);
    STAGE(0, 0);
    STAGE(1, 1);
    SYNC_VM(0);

    const int p0 = (2 * kg) ^ (lrow & 7);   // read-side swizzle
    const int p1 = p0 ^ 1;

    // per-iter vmem issue: 4 B-loads (kt+1) + 2 gload_lds (kt+2) = 6.
    // At end-of-kt barrier, stage(kt+1) (issued last iter, older than all 6)
    // must be done -> vmcnt(6). Tail: kt=14 issues only B(15) -> vmcnt(4).
    #pragma unroll
    for (int kt = 0; kt < KT_TILES; ++kt) {
        const int cur = kt % 3;
        if (kt + 1 < KT_TILES) {
            #pragma unroll
            for (int n = 0; n < 4; ++n)
                bfr[(kt + 1) & 1][n] =
                    *(const bf16x8*)(wfp[n] + (size_t)(kt + 1) * WFRAG_KT_STRIDE);
        }
        if (kt + 2 < KT_TILES) STAGE(kt + 2, (kt + 2) % 3);

        bf16x8 af[4];
        #pragma unroll
        for (int m = 0; m < 4; ++m) {
            const int row = wr * 64 + m * 16 + lrow;
            const f32x4 v0 = *(const f32x4*)&At[cur][row][p0 * 4];
            const f32x4 v1 = *(const f32x4*)&At[cur][row][p1 * 4];
            union { bf16x8 v; uint32_t u[4]; } c_;
            c_.u[0] = cvt_pk_bf16(v0[0], v0[1]);
            c_.u[1] = cvt_pk_bf16(v0[2], v0[3]);
            c_.u[2] = cvt_pk_bf16(v1[0], v1[1]);
            c_.u[3] = cvt_pk_bf16(v1[2], v1[3]);
            af[m] = c_.v;
        }
        #pragma unroll
        for (int m = 0; m < 4; ++m)
            #pragma unroll
            for (int n = 0; n < 4; ++n)
                acc[m][n] = __builtin_amdgcn_mfma_f32_16x16x32_bf16(
                    af[m], bfr[kt & 1][n], acc[m][n], 0, 0, 0);

        if (kt <= KT_TILES - 3)       SYNC_VM(6);
        else if (kt == KT_TILES - 2)  SYNC_VM(4);
        // kt == KT_TILES-1: no barrier (epilogue __syncthreads follows)
    }
#undef STAGE

    __syncthreads();   // full drain before LDS reuse

    uint16_t* ep = (uint16_t*)smem_raw;
    const int wbase = wid * (16 * EPS);
    float bv[4];
    #pragma unroll
    for (int n = 0; n < 4; ++n) bv[n] = bias[wc * 64 + n * 16 + lrow];

    #pragma unroll
    for (int m = 0; m < 4; ++m) {
        #pragma unroll
        for (int n = 0; n < 4; ++n)
            #pragma unroll
            for (int j = 0; j < 4; ++j)
                ep[wbase + (kg * 4 + j) * EPS + n * 16 + lrow] = f2bf(acc[m][n][j] + bv[n]);
        __syncthreads();
        #pragma unroll
        for (int g = 0; g < 4; ++g) {
            const int r16  = g * 4 + (lane >> 4);
            const int cidx = (lane & 15) * 4;
            const int ib = wbase + r16 * EPS + cidx;
            uint2 v;
            v.x = *(const uint32_t*)&ep[ib];
            v.y = *(const uint32_t*)&ep[ib + 2];
            const int row = m0 + wr * 64 + m * 16 + r16;
            if (row < N_NODES)
                *(uint2*)(h + (size_t)row * OUT_F + wc * 64 + cidx) = v;
        }
        __syncthreads();
    }
}

// ================= bucketed CSR build (fixed-capacity, no count/scan) =======
__global__ void bucket_init_kernel(int* __restrict__ bucket_cursor)
{
    const int i = threadIdx.x;
    if (i < NBUCK) bucket_cursor[i] = i * BCAP;
}

// scatter packed (src<<9 | dst&511) into padded bucket-major order.
// Block reserves per-bucket ranges with ONE global atomic per bucket.
__global__ __launch_bounds__(256) void bucket_scatter_kernel(
    const int* __restrict__ src, const int* __restrict__ dst,
    int* __restrict__ bucket_cursor, uint32_t* __restrict__ pairs)
{
    __shared__ int bh[NBUCK];
    __shared__ int bbase[NBUCK];
    for (int i = threadIdx.x; i < NBUCK; i += 256) bh[i] = 0;
    __syncthreads();
    const int base = blockIdx.x * SC_EDGES;
    uint32_t pk[SC_EDGES / 256];
    int      bk[SC_EDGES / 256];
    #pragma unroll
    for (int k = 0; k < SC_EDGES / 256; ++k) {
        const int e = base + k * 256 + threadIdx.x;
        if (e < N_EDGES) {
            const int d = dst[e], s = src[e];
            bk[k] = d >> 9;
            pk[k] = ((uint32_t)s << 9) | (uint32_t)(d & 511);
            atomicAdd(&bh[bk[k]], 1);
        } else {
            bk[k] = -1; pk[k] = 0;
        }
    }
    __syncthreads();
    for (int i = threadIdx.x; i < NBUCK; i += 256) {
        const int c = bh[i];
        bbase[i] = c ? atomicAdd(&bucket_cursor[i], c) : 0;
        bh[i] = 0;
    }
    __syncthreads();
    #pragma unroll
    for (int k = 0; k < SC_EDGES / 256; ++k) {
        if (bk[k] >= 0) {
            const int r = atomicAdd(&bh[bk[k]], 1);
            pairs[bbase[bk[k]] + r] = pk[k];
        }
    }
}

// per-bucket counting sort -> start[] + deg[] + csr_src (padded regions)
__global__ __launch_bounds__(256) void bucket_sort_kernel(
    const uint32_t* __restrict__ pairs, const int* __restrict__ bucket_cursor,
    int* __restrict__ start, int* __restrict__ deg, int* __restrict__ csr_src)
{
    __shared__ int hist[512];
    __shared__ int tsum[256];
    const int b = blockIdx.x;
    const int t = threadIdx.x;
    const int ebeg = b * BCAP;
    const int eend = bucket_cursor[b];   // = b*BCAP + count after scatter
    hist[t] = 0; hist[t + 256] = 0;
    __syncthreads();
    for (int i = ebeg + t; i < eend; i += 256)
        atomicAdd(&hist[pairs[i] & 511], 1);
    __syncthreads();
    const int c0 = hist[2 * t], c1 = hist[2 * t + 1];
    int x = c0 + c1;
    tsum[t] = x; __syncthreads();
    for (int off = 1; off < 256; off <<= 1) {
        const int y = (t >= off) ? tsum[t - off] : 0;
        __syncthreads();
        x += y; tsum[t] = x;
        __syncthreads();
    }
    const int ex = x - (c0 + c1);     // exclusive prefix over thread pairs
    __syncthreads();                  // all c0/c1 reads done before overwrite
    hist[2 * t] = ex;
    hist[2 * t + 1] = ex + c0;
    const int nb0 = b << 9;
    if (nb0 + 2 * t < N_NODES) {
        start[nb0 + 2 * t] = ebeg + ex;
        deg[nb0 + 2 * t]   = c0;
    }
    if (nb0 + 2 * t + 1 < N_NODES) {
        start[nb0 + 2 * t + 1] = ebeg + ex + c0;
        deg[nb0 + 2 * t + 1]   = c1;
    }
    __syncthreads();
    for (int i = ebeg + t; i < eend; i += 256) {
        const uint32_t p = pairs[i];
        const int pos = ebeg + atomicAdd(&hist[p & 511], 1);
        csr_src[pos] = (int)(p >> 9);
    }
}

// ---------------- gather (v2): half-wave per row, 16B/lane ----------------
__global__ __launch_bounds__(256) void gcn_gather_kernel(
    const uint16_t* __restrict__ h, const int* __restrict__ start,
    const int* __restrict__ deg, const int* __restrict__ csr_src,
    float* __restrict__ out)
{
    const int n = blockIdx.x * 4 + (threadIdx.x >> 6);
    if (n >= N_NODES) return;
    const int lane = threadIdx.x & 63;
    const int half = lane >> 5;
    const int hl   = lane & 31;
    const int beg = start[n];
    const int end = beg + deg[n];

    float a[8] = {0.f, 0.f, 0.f, 0.f, 0.f, 0.f, 0.f, 0.f};

    int j = beg + half;
    for (; j + 2 < end; j += 4) {   // 2 edges per half per iter
        const int s0 = csr_src[j];
        const int s1 = csr_src[j + 2];
        const u16x8 v0 = *(const u16x8*)(h + (size_t)s0 * OUT_F + hl * 8);
        const u16x8 v1 = *(const u16x8*)(h + (size_t)s1 * OUT_F + hl * 8);
        #pragma unroll
        for (int i = 0; i < 8; ++i) a[i] += bf2f(v0[i]);
        #pragma unroll
        for (int i = 0; i < 8; ++i) a[i] += bf2f(v1[i]);
    }
    if (j < end) {
        const int s0 = csr_src[j];
        const u16x8 v0 = *(const u16x8*)(h + (size_t)s0 * OUT_F + hl * 8);
        #pragma unroll
        for (int i = 0; i < 8; ++i) a[i] += bf2f(v0[i]);
    }

    #pragma unroll
    for (int i = 0; i < 8; ++i) a[i] += __shfl_xor(a[i], 32, 64);

    if (half == 0) {
        f32x4 o0, o1;
        o0[0] = a[0]; o0[1] = a[1]; o0[2] = a[2]; o0[3] = a[3];
        o1[0] = a[4]; o1[1] = a[5]; o1[2] = a[6]; o1[3] = a[7];
        float* op = out + (size_t)n * OUT_F + hl * 8;
        *(f32x4*)op = o0;
        *(f32x4*)(op + 4) = o1;
    }
}

// ---------------- fallback atomic scatter (tiny ws) ----------------
__global__ __launch_bounds__(256) void gcn_scatter_kernel(
    const uint16_t* __restrict__ h, const int* __restrict__ src,
    const int* __restrict__ dst, float* __restrict__ out)
{
    const int e = (blockIdx.x << 2) | (threadIdx.x >> 6);
    if (e >= N_EDGES) return;
    const int lane = threadIdx.x & 63;
    const int s = src[e];
    const int d = dst[e];
    const ushort4 v = *((const ushort4*)(h + (size_t)s * OUT_F) + lane);
    float* op = out + (size_t)d * OUT_F + (lane << 2);
    unsafeAtomicAdd(op + 0, bf2f(v.x));
    unsafeAtomicAdd(op + 1, bf2f(v.y));
    unsafeAtomicAdd(op + 2, bf2f(v.z));
    unsafeAtomicAdd(op + 3, bf2f(v.w));
}

static inline size_t align256(size_t x) { return (x + 255) & ~(size_t)255; }

extern "C" void kernel_launch(void* const* d_in, const int* in_sizes, int n_in,
                              void* d_out, int out_size, void* d_ws, size_t ws_size,
                              hipStream_t stream) {
    const float* feat = (const float*)d_in[0];
    const float* W    = (const float*)d_in[1];
    const float* bias = (const float*)d_in[2];
    const int*   src  = (const int*)d_in[3];
    const int*   dst  = (const int*)d_in[4];
    float*       out  = (float*)d_out;

    char* ws = (char*)d_ws;

    size_t off = 0;
    uint16_t* h       = (uint16_t*)(ws + off); off = align256(off + (size_t)N_NODES * OUT_F * 2);
    uint16_t* w_frag  = (uint16_t*)(ws + off); off = align256(off + (size_t)OUT_F * IN_F * 2);
    int* start        = (int*)(ws + off);      off = align256(off + (size_t)N_NODES * 4);
    int* deg          = (int*)(ws + off);      off = align256(off + (size_t)N_NODES * 4);
    int* bucket_cursor= (int*)(ws + off);      off = align256(off + (size_t)NBUCK * 4);
    uint32_t* pairs   = (uint32_t*)(ws + off); off = align256(off + (size_t)NBUCK * BCAP * 4);
    int* csr_src      = (int*)(ws + off);      off = align256(off + (size_t)NBUCK * BCAP * 4);
    const bool bucket_ok = (off <= ws_size);

    const int mtiles = (N_NODES + BM - 1) / BM;  // 782

    w_frag_kernel<<<64, 256, 0, stream>>>(W, w_frag);
    gcn_gemm_kernel<<<mtiles, 512, 0, stream>>>(feat, w_frag, bias, h);

    if (bucket_ok) {
        bucket_init_kernel<<<1, 256, 0, stream>>>(bucket_cursor);
        bucket_scatter_kernel<<<NBLK_SC, 256, 0, stream>>>(src, dst, bucket_cursor, pairs);
        bucket_sort_kernel<<<NBUCK, 256, 0, stream>>>(pairs, bucket_cursor, start, deg, csr_src);
        gcn_gather_kernel<<<(N_NODES + 3) / 4, 256, 0, stream>>>(h, start, deg, csr_src, out);
    } else {
        hipMemsetAsync(out, 0, (size_t)out_size * sizeof(float), stream);
        gcn_scatter_kernel<<<(N_EDGES + 3) / 4, 256, 0, stream>>>(h, src, dst, out);
    }
}

// Round 13
// 216.263 us; speedup vs baseline: 1.2787x; 1.1371x over previous
//
#include <hip/hip_runtime.h>
#include <hip/hip_bf16.h>
#include <stdint.h>

#define N_NODES 100000
#define IN_F    512
#define OUT_F   256
#define N_EDGES 1600000

typedef __attribute__((ext_vector_type(4))) float f32x4;
typedef __attribute__((ext_vector_type(8))) short bf16x8;
typedef __attribute__((ext_vector_type(8))) uint16_t u16x8;
typedef __attribute__((ext_vector_type(4))) uint32_t u32x4;

#define BM 128
#define BK 32
#define KT_TILES (IN_F / BK)             // 16
#define WFRAG_KT_STRIDE (16 * 16 * 32)   // 8192 elems per kt slab
#define EPS 66                            // epilogue LDS row stride (bf16)
#define MTILES ((N_NODES + BM - 1) / BM)  // 782

#define NBUCK 391                         // ceil(100000/256) buckets of 256 nodes
#define BCAP  4608                        // mean ~4092, +8 sigma
#define SC_EDGES 8192                     // edges per scatter block
#define NBLK_SC ((N_EDGES + SC_EDGES - 1) / SC_EDGES)   // 196

__device__ __forceinline__ float bf2f(uint16_t u) {
    union { uint32_t i; float f; } c; c.i = ((uint32_t)u) << 16; return c.f;
}
__device__ __forceinline__ uint16_t f2bf(float f) {
    union { float f; uint32_t i; } c; c.f = f;
    uint32_t x = c.i;
    return (uint16_t)((x + 0x7FFFu + ((x >> 16) & 1u)) >> 16);  // RNE
}
__device__ __forceinline__ uint32_t cvt_pk_bf16(float a, float b) {
    uint32_t r;
    asm("v_cvt_pk_bf16_f32 %0, %1, %2" : "=v"(r) : "v"(a), "v"(b));
    return r;
}
// async global->LDS, 16B per lane; LDS dest = wave-uniform base + lane*16
__device__ __forceinline__ void gload_lds16(const float* g, float* l) {
    __builtin_amdgcn_global_load_lds(
        (const __attribute__((address_space(1))) void*)g,
        (__attribute__((address_space(3))) void*)l, 16, 0, 0);
}
// counted-vmcnt barrier (proven R11): wait until only N vmem ops remain.
#define SYNC_VM(N) do {                                        \
    asm volatile("s_waitcnt vmcnt(" #N ")" ::: "memory");      \
    __builtin_amdgcn_s_barrier();                              \
} while (0)

// ---------------- W -> bf16 fragment-order ----------------
__global__ __launch_bounds__(256) void w_frag_kernel(
    const float* __restrict__ W, uint16_t* __restrict__ w_frag)
{
    const int gid = blockIdx.x * 256 + threadIdx.x;   // 16384 groups of 8 elems
    if (gid >= 16384) return;
    const int kg = gid & 3, lrow = (gid >> 2) & 15, cg = (gid >> 6) & 15, kt = gid >> 10;
    const float* s = W + (size_t)(cg * 16 + lrow) * IN_F + kt * 32 + kg * 8;
    const f32x4 v0 = *(const f32x4*)s;
    const f32x4 v1 = *(const f32x4*)(s + 4);
    u32x4 c;
    c[0] = cvt_pk_bf16(v0[0], v0[1]);
    c[1] = cvt_pk_bf16(v0[2], v0[3]);
    c[2] = cvt_pk_bf16(v1[0], v1[1]);
    c[3] = cvt_pk_bf16(v1[2], v1[3]);
    *(u32x4*)(w_frag + (size_t)gid * 8) = c;
}

__global__ __launch_bounds__(512) void bucket_init_kernel(int* __restrict__ bucket_cursor)
{
    const int i = threadIdx.x;
    if (i < NBUCK) bucket_cursor[i] = i * BCAP;
}

// ---------------- fused GEMM + edge-scatter ----------------
// blocks [0, MTILES): GEMM  h = bf16(feat @ W^T + b)  (R11-proven pipeline,
//   R11-proven epilogue WITH barriers).
// blocks [MTILES, MTILES+NBLK_SC): scatter packed (src<<8|dst&255) into
//   padded bucket-major `pairs` (runs concurrently in the GEMM drain tail).
__global__ __launch_bounds__(512) void gemm_scatter_kernel(
    const float* __restrict__ feat, const uint16_t* __restrict__ w_frag,
    const float* __restrict__ bias, uint16_t* __restrict__ h,
    const int* __restrict__ src, const int* __restrict__ dst,
    int* __restrict__ bucket_cursor, uint32_t* __restrict__ pairs)
{
    __shared__ __align__(16) char smem_raw[3 * BM * BK * 4];   // 48 KB

    if (blockIdx.x >= MTILES) {
        // ================= scatter path =================
        int* bh    = (int*)smem_raw;           // [NBUCK]
        int* bbase = bh + NBUCK;               // [NBUCK]
        const int tid = threadIdx.x;
        for (int i = tid; i < NBUCK; i += 512) bh[i] = 0;
        __syncthreads();
        const int base = (int)(blockIdx.x - MTILES) * SC_EDGES;
        uint32_t pk[SC_EDGES / 512];
        int      bk[SC_EDGES / 512];
        #pragma unroll
        for (int k = 0; k < SC_EDGES / 512; ++k) {
            const int e = base + k * 512 + tid;
            if (e < N_EDGES) {
                const int d = dst[e], s = src[e];
                bk[k] = d >> 8;
                pk[k] = ((uint32_t)s << 8) | (uint32_t)(d & 255);
                atomicAdd(&bh[bk[k]], 1);
            } else {
                bk[k] = -1; pk[k] = 0;
            }
        }
        __syncthreads();
        for (int i = tid; i < NBUCK; i += 512) {
            const int c = bh[i];
            bbase[i] = c ? atomicAdd(&bucket_cursor[i], c) : 0;
            bh[i] = 0;
        }
        __syncthreads();
        #pragma unroll
        for (int k = 0; k < SC_EDGES / 512; ++k) {
            if (bk[k] >= 0) {
                const int r = atomicAdd(&bh[bk[k]], 1);
                pairs[bbase[bk[k]] + r] = pk[k];
            }
        }
        return;
    }

    // ================= GEMM path =================
    float (*At)[BM][BK] = (float (*)[BM][BK])smem_raw;

    const int m0 = blockIdx.x * BM;

    const int t    = threadIdx.x;
    const int wid  = t >> 6;
    const int lane = t & 63;
    const int wr   = wid >> 2, wc = wid & 3;   // 2x4 waves, 64x64 tile per wave
    const int lrow = lane & 15;
    const int kg   = lane >> 4;

    f32x4 acc[4][4] = {};

    const int r8 = lane >> 3;
    const int sp = lane & 7;
    const int sc = sp ^ r8;            // source-side swizzle
    const float* gsrc[2];
    #pragma unroll
    for (int i = 0; i < 2; ++i) {
        int grow = m0 + wid * 16 + i * 8 + r8;
        if (grow > N_NODES - 1) grow = N_NODES - 1;
        gsrc[i] = feat + (size_t)grow * IN_F + sc * 4;
    }

#define STAGE(KT, BUF)                                                     \
    do {                                                                   \
        gload_lds16(gsrc[0] + (KT) * BK, &At[BUF][wid * 16][0]);           \
        gload_lds16(gsrc[1] + (KT) * BK, &At[BUF][wid * 16 + 8][0]);       \
    } while (0)

    const uint16_t* wfp[4];
    #pragma unroll
    for (int n = 0; n < 4; ++n) {
        const int cg = wc * 4 + n;
        wfp[n] = w_frag + ((size_t)cg * 16 + lrow) * 32 + kg * 8;
    }

    bf16x8 bfr[2][4];

    // prologue: B(0), stage tiles 0 and 1; single full drain
    #pragma unroll
    for (int n = 0; n < 4; ++n) bfr[0][n] = *(const bf16x8*)(wfp[n]);
    STAGE(0, 0);
    STAGE(1, 1);
    SYNC_VM(0);

    const int p0 = (2 * kg) ^ (lrow & 7);   // read-side swizzle
    const int p1 = p0 ^ 1;

    // per-iter vmem issue: 4 B-loads (kt+1) + 2 gload_lds (kt+2) = 6.
    #pragma unroll
    for (int kt = 0; kt < KT_TILES; ++kt) {
        const int cur = kt % 3;
        if (kt + 1 < KT_TILES) {
            #pragma unroll
            for (int n = 0; n < 4; ++n)
                bfr[(kt + 1) & 1][n] =
                    *(const bf16x8*)(wfp[n] + (size_t)(kt + 1) * WFRAG_KT_STRIDE);
        }
        if (kt + 2 < KT_TILES) STAGE(kt + 2, (kt + 2) % 3);

        bf16x8 af[4];
        #pragma unroll
        for (int m = 0; m < 4; ++m) {
            const int row = wr * 64 + m * 16 + lrow;
            const f32x4 v0 = *(const f32x4*)&At[cur][row][p0 * 4];
            const f32x4 v1 = *(const f32x4*)&At[cur][row][p1 * 4];
            union { bf16x8 v; uint32_t u[4]; } c_;
            c_.u[0] = cvt_pk_bf16(v0[0], v0[1]);
            c_.u[1] = cvt_pk_bf16(v0[2], v0[3]);
            c_.u[2] = cvt_pk_bf16(v1[0], v1[1]);
            c_.u[3] = cvt_pk_bf16(v1[2], v1[3]);
            af[m] = c_.v;
        }
        #pragma unroll
        for (int m = 0; m < 4; ++m)
            #pragma unroll
            for (int n = 0; n < 4; ++n)
                acc[m][n] = __builtin_amdgcn_mfma_f32_16x16x32_bf16(
                    af[m], bfr[kt & 1][n], acc[m][n], 0, 0, 0);

        if (kt <= KT_TILES - 3)       SYNC_VM(6);
        else if (kt == KT_TILES - 2)  SYNC_VM(4);
    }
#undef STAGE

    __syncthreads();   // full drain before LDS reuse

    // epilogue (R11-proven): per-wave 64x64 transpose through LDS with
    // explicit barriers — the cross-lane LDS RAW needs them (R12 lesson).
    uint16_t* ep = (uint16_t*)smem_raw;
    const int wbase = wid * (16 * EPS);
    float bv[4];
    #pragma unroll
    for (int n = 0; n < 4; ++n) bv[n] = bias[wc * 64 + n * 16 + lrow];

    #pragma unroll
    for (int m = 0; m < 4; ++m) {
        #pragma unroll
        for (int n = 0; n < 4; ++n)
            #pragma unroll
            for (int j = 0; j < 4; ++j)
                ep[wbase + (kg * 4 + j) * EPS + n * 16 + lrow] = f2bf(acc[m][n][j] + bv[n]);
        __syncthreads();
        #pragma unroll
        for (int g = 0; g < 4; ++g) {
            const int r16  = g * 4 + (lane >> 4);
            const int cidx = (lane & 15) * 4;
            const int ib = wbase + r16 * EPS + cidx;
            uint2 v;
            v.x = *(const uint32_t*)&ep[ib];
            v.y = *(const uint32_t*)&ep[ib + 2];
            const int row = m0 + wr * 64 + m * 16 + r16;
            if (row < N_NODES)
                *(uint2*)(h + (size_t)row * OUT_F + wc * 64 + cidx) = v;
        }
        __syncthreads();
    }
}

// ---------------- per-bucket counting sort: 1 node per thread ----------------
__global__ __launch_bounds__(256) void bucket_sort_kernel(
    const uint32_t* __restrict__ pairs, const int* __restrict__ bucket_cursor,
    int* __restrict__ start, int* __restrict__ deg, int* __restrict__ csr_src)
{
    __shared__ int hist[256];
    __shared__ int cur[256];
    __shared__ int tsum[256];
    const int b = blockIdx.x;
    const int t = threadIdx.x;
    const int ebeg = b * BCAP;
    const int eend = bucket_cursor[b];   // = b*BCAP + count after scatter
    hist[t] = 0;
    __syncthreads();
    for (int i = ebeg + t; i < eend; i += 256)
        atomicAdd(&hist[pairs[i] & 255], 1);
    __syncthreads();
    const int c = hist[t];
    int x = c;
    tsum[t] = x; __syncthreads();
    for (int off = 1; off < 256; off <<= 1) {
        const int y = (t >= off) ? tsum[t - off] : 0;
        __syncthreads();
        x += y; tsum[t] = x;
        __syncthreads();
    }
    const int ex = x - c;               // exclusive prefix
    const int node = (b << 8) + t;
    if (node < N_NODES) {
        start[node] = ebeg + ex;
        deg[node]   = c;
    }
    cur[t] = ebeg + ex;
    __syncthreads();
    for (int i = ebeg + t; i < eend; i += 256) {
        const uint32_t p = pairs[i];
        const int pos = atomicAdd(&cur[p & 255], 1);
        csr_src[pos] = (int)(p >> 8);
    }
}

// ---------------- gather (v2, at measured floor): half-wave per row ----------
__global__ __launch_bounds__(256) void gcn_gather_kernel(
    const uint16_t* __restrict__ h, const int* __restrict__ start,
    const int* __restrict__ deg, const int* __restrict__ csr_src,
    float* __restrict__ out)
{
    const int n = blockIdx.x * 4 + (threadIdx.x >> 6);
    if (n >= N_NODES) return;
    const int lane = threadIdx.x & 63;
    const int half = lane >> 5;
    const int hl   = lane & 31;
    const int beg = start[n];
    const int end = beg + deg[n];

    float a[8] = {0.f, 0.f, 0.f, 0.f, 0.f, 0.f, 0.f, 0.f};

    int j = beg + half;
    for (; j + 2 < end; j += 4) {
        const int s0 = csr_src[j];
        const int s1 = csr_src[j + 2];
        const u16x8 v0 = *(const u16x8*)(h + (size_t)s0 * OUT_F + hl * 8);
        const u16x8 v1 = *(const u16x8*)(h + (size_t)s1 * OUT_F + hl * 8);
        #pragma unroll
        for (int i = 0; i < 8; ++i) a[i] += bf2f(v0[i]);
        #pragma unroll
        for (int i = 0; i < 8; ++i) a[i] += bf2f(v1[i]);
    }
    if (j < end) {
        const int s0 = csr_src[j];
        const u16x8 v0 = *(const u16x8*)(h + (size_t)s0 * OUT_F + hl * 8);
        #pragma unroll
        for (int i = 0; i < 8; ++i) a[i] += bf2f(v0[i]);
    }

    #pragma unroll
    for (int i = 0; i < 8; ++i) a[i] += __shfl_xor(a[i], 32, 64);

    if (half == 0) {
        f32x4 o0, o1;
        o0[0] = a[0]; o0[1] = a[1]; o0[2] = a[2]; o0[3] = a[3];
        o1[0] = a[4]; o1[1] = a[5]; o1[2] = a[6]; o1[3] = a[7];
        float* op = out + (size_t)n * OUT_F + hl * 8;
        *(f32x4*)op = o0;
        *(f32x4*)(op + 4) = o1;
    }
}

// ---------------- fallback: atomic scatter (tiny ws) ------------
__global__ __launch_bounds__(256) void gcn_scatter_kernel(
    const uint16_t* __restrict__ h, const int* __restrict__ src,
    const int* __restrict__ dst, float* __restrict__ out)
{
    const int e = (blockIdx.x << 2) | (threadIdx.x >> 6);
    if (e >= N_EDGES) return;
    const int lane = threadIdx.x & 63;
    const int s = src[e];
    const int d = dst[e];
    const ushort4 v = *((const ushort4*)(h + (size_t)s * OUT_F) + lane);
    float* op = out + (size_t)d * OUT_F + (lane << 2);
    unsafeAtomicAdd(op + 0, bf2f(v.x));
    unsafeAtomicAdd(op + 1, bf2f(v.y));
    unsafeAtomicAdd(op + 2, bf2f(v.z));
    unsafeAtomicAdd(op + 3, bf2f(v.w));
}

static inline size_t align256(size_t x) { return (x + 255) & ~(size_t)255; }

extern "C" void kernel_launch(void* const* d_in, const int* in_sizes, int n_in,
                              void* d_out, int out_size, void* d_ws, size_t ws_size,
                              hipStream_t stream) {
    const float* feat = (const float*)d_in[0];
    const float* W    = (const float*)d_in[1];
    const float* bias = (const float*)d_in[2];
    const int*   src  = (const int*)d_in[3];
    const int*   dst  = (const int*)d_in[4];
    float*       out  = (float*)d_out;

    char* ws = (char*)d_ws;

    size_t off = 0;
    uint16_t* h       = (uint16_t*)(ws + off); off = align256(off + (size_t)N_NODES * OUT_F * 2);
    uint16_t* w_frag  = (uint16_t*)(ws + off); off = align256(off + (size_t)OUT_F * IN_F * 2);
    int* start        = (int*)(ws + off);      off = align256(off + (size_t)N_NODES * 4);
    int* deg          = (int*)(ws + off);      off = align256(off + (size_t)N_NODES * 4);
    int* bucket_cursor= (int*)(ws + off);      off = align256(off + (size_t)NBUCK * 4);
    uint32_t* pairs   = (uint32_t*)(ws + off); off = align256(off + (size_t)NBUCK * BCAP * 4);
    int* csr_src      = (int*)(ws + off);      off = align256(off + (size_t)NBUCK * BCAP * 4);
    const bool bucket_ok = (off <= ws_size);

    w_frag_kernel<<<64, 256, 0, stream>>>(W, w_frag);

    if (bucket_ok) {
        bucket_init_kernel<<<1, 512, 0, stream>>>(bucket_cursor);
        gemm_scatter_kernel<<<MTILES + NBLK_SC, 512, 0, stream>>>(
            feat, w_frag, bias, h, src, dst, bucket_cursor, pairs);
        bucket_sort_kernel<<<NBUCK, 256, 0, stream>>>(pairs, bucket_cursor, start, deg, csr_src);
        gcn_gather_kernel<<<(N_NODES + 3) / 4, 256, 0, stream>>>(h, start, deg, csr_src, out);
    } else {
        gemm_scatter_kernel<<<MTILES, 512, 0, stream>>>(
            feat, w_frag, bias, h, src, dst, (int*)d_ws, (uint32_t*)d_ws);
        hipMemsetAsync(out, 0, (size_t)out_size * sizeof(float), stream);
        gcn_scatter_kernel<<<(N_EDGES + 3) / 4, 256, 0, stream>>>(h, src, dst, out);
    }
}